// Round 11
// baseline (166.941 us; speedup 1.0000x reference)
//
#include <hip/hip_runtime.h>

using u16    = unsigned short;
using f32x4  = __attribute__((ext_vector_type(4))) float;
using bf16x8 = __attribute__((ext_vector_type(8))) __bf16;

#define E_CNT 400000
#define G_CNT 1024
#define NNODE 65536

// ws layout (bytes)
#define WS_HGF   0u          // [1024][128] f32 (permuted, +b1)  = 524288
#define WS_WFRAG 524288u     // [16][8][64] x 16B bf16 W1c frags = 131072
#define WS_CT    655360u     // [8][128] f32 (permuted)          =   4096
#define WS_NMEH  659456u     // [128] f32 (permuted)             =    512
#define WS_BINS  660480u     // [65536] int                      = 262144
#define WS_OFFS  922624u     // [65537] int                      = 262148
#define WS_CURS  1184772u    // [65536] int                      = 262144
#define WS_EID   1446916u    // [400000] int (e | rg<<20)        = 1600000

__device__ __forceinline__ u16 f2bf(float f) {
  unsigned u = __builtin_bit_cast(unsigned, f);
  return (u16)((u + 0x7fffu + ((u >> 16) & 1u)) >> 16);  // RNE
}
__device__ __forceinline__ uint4 pack8(f32x4 a, f32x4 b) {
  uint4 r;
  r.x = (unsigned)f2bf(a[0]) | ((unsigned)f2bf(a[1]) << 16);
  r.y = (unsigned)f2bf(a[2]) | ((unsigned)f2bf(a[3]) << 16);
  r.z = (unsigned)f2bf(b[0]) | ((unsigned)f2bf(b[1]) << 16);
  r.w = (unsigned)f2bf(b[2]) | ((unsigned)f2bf(b[3]) << 16);
  return r;
}
__device__ __forceinline__ float w1c(const float* sW1, const float* tW1, int k, int j) {
  return (j < 64) ? sW1[(size_t)k * 64 + j] : tW1[(size_t)k * 64 + (j - 64)];
}
// 16-lane sum via DPP (per 16-lane row group, VALU pipe only)
__device__ __forceinline__ float dpp_red16(float x) {
  int v;
  v = __builtin_amdgcn_update_dpp(0, __builtin_bit_cast(int, x), 0xB1, 0xF, 0xF, false);
  x += __builtin_bit_cast(float, v);
  v = __builtin_amdgcn_update_dpp(0, __builtin_bit_cast(int, x), 0x4E, 0xF, 0xF, false);
  x += __builtin_bit_cast(float, v);
  v = __builtin_amdgcn_update_dpp(0, __builtin_bit_cast(int, x), 0x141, 0xF, 0xF, false);
  x += __builtin_bit_cast(float, v);
  v = __builtin_amdgcn_update_dpp(0, __builtin_bit_cast(int, x), 0x140, 0xF, 0xF, false);
  x += __builtin_bit_cast(float, v);
  return x;
}
// select component rg (uniform per slice-iteration) from f32x4 -- static
// indices only (rule 20), 3 cndmask.
__device__ __forceinline__ float sel4(f32x4 a, int rg) {
  float x01 = (rg & 1) ? a[1] : a[0];
  float x23 = (rg & 1) ? a[3] : a[2];
  return (rg & 2) ? x23 : x01;
}

// ---------- k_prep: WFRAG + tables + zero bins ----------
__global__ __launch_bounds__(256) void k_prep(const float* __restrict__ nme,
                                              const float* __restrict__ sW1,
                                              const float* __restrict__ tW1,
                                              const float* __restrict__ sW2,
                                              const float* __restrict__ tW2,
                                              u16* __restrict__ wfrag,
                                              float* __restrict__ ct,
                                              float* __restrict__ nmeh,
                                              int* __restrict__ bins) {
  int b = blockIdx.x;
  if (b < 256) {
    int idx = b * 256 + threadIdx.x;  // 65536 total
    int j = idx & 7, l = (idx >> 3) & 63, fn = (idx >> 9) & 7, c = idx >> 12;
    int col = fn * 16 + (l & 15);
    int k = c * 32 + (l >> 4) * 8 + j;
    wfrag[idx] = f2bf(w1c(sW1, tW1, k, col));
  } else if (b == 256) {
    int p = threadIdx.x;
    if (p >= 128) return;
    int q = p >> 3, i = p & 7, j = i * 16 + q;
    ct[0 * 128 + p] = w1c(sW1, tW1, 513, j);
    ct[1 * 128 + p] = w1c(sW1, tW1, 514, j);
    ct[2 * 128 + p] = w1c(sW1, tW1, 515, j);
    ct[3 * 128 + p] = (i < 4) ? sW2[j] : 0.f;
    if (i >= 4) {
      int jj = j - 64;
      ct[4 * 128 + p] = tW2[jj * 3 + 0];
      ct[5 * 128 + p] = tW2[jj * 3 + 1];
      ct[6 * 128 + p] = tW2[jj * 3 + 2];
    } else {
      ct[4 * 128 + p] = 0.f; ct[5 * 128 + p] = 0.f; ct[6 * 128 + p] = 0.f;
    }
    ct[7 * 128 + p] = w1c(sW1, tW1, 512, j);
    float s = 0.f;
    for (int k = 0; k < 132; ++k) s += nme[k] * w1c(sW1, tW1, 384 + k, j);
    nmeh[p] = s;
  } else {  // blocks 257..320: zero bins (64 blocks x 256 thr x 4 ints)
    int idx4 = (b - 257) * 256 + threadIdx.x;
    *(int4*)(bins + idx4 * 4) = make_int4(0, 0, 0, 0);
  }
}

// ---------- k_hist: bins[t] = edge count per target node ----------
__global__ __launch_bounds__(256) void k_hist(const int* __restrict__ tgt,
                                              int* __restrict__ bins) {
  int e = blockIdx.x * 256 + threadIdx.x;
  if (e < E_CNT) atomicAdd(&bins[tgt[e]], 1);
}

// ---------- k_scan: exclusive prefix over 65536 bins -> offs, curs ----------
__global__ __launch_bounds__(1024) void k_scan(const int* __restrict__ bins,
                                               int* __restrict__ offs,
                                               int* __restrict__ curs) {
  __shared__ int wsum[16];
  int t = threadIdx.x;
  int b0 = t * 64;
  int loc[64];
#pragma unroll
  for (int k = 0; k < 64; ++k) loc[k] = bins[b0 + k];
  int s = 0;
#pragma unroll
  for (int k = 0; k < 64; ++k) s += loc[k];
  // inclusive wave scan of per-thread sums
  int lane = t & 63, w = t >> 6;
  int v = s;
#pragma unroll
  for (int d = 1; d < 64; d <<= 1) {
    int u = __shfl_up(v, d, 64);
    if (lane >= d) v += u;
  }
  if (lane == 63) wsum[w] = v;
  __syncthreads();
  if (t == 0) {
    int a = 0;
#pragma unroll
    for (int k = 0; k < 16; ++k) { int x = wsum[k]; wsum[k] = a; a += x; }
  }
  __syncthreads();
  int run = wsum[w] + (v - s);  // exclusive prefix for this thread's bins
#pragma unroll
  for (int k = 0; k < 64; ++k) {
    offs[b0 + k] = run;
    curs[b0 + k] = run;
    run += loc[k];
  }
  if (t == 1023) offs[NNODE] = run;  // = E_CNT
}

// ---------- k_scatter: eid sorted by target; pack rg = t&3 in bits 20-21 ----
__global__ __launch_bounds__(256) void k_scatter(const int* __restrict__ tgt,
                                                 int* __restrict__ curs,
                                                 int* __restrict__ eid) {
  int e = blockIdx.x * 256 + threadIdx.x;
  if (e >= E_CNT) return;
  int t = tgt[e];
  int pos = atomicAdd(&curs[t], 1);
  eid[pos] = e | ((t & 3) << 20);
}

// ---------- H_gf[1024][128] f32 (+b1) permuted, with STOP head fused -------
__global__ __launch_bounds__(64) void k_hgf(const float* __restrict__ imr,
                                            const float* __restrict__ pgr,
                                            const float* __restrict__ nr,
                                            const int* __restrict__ focus,
                                            const u16* __restrict__ wfrag,
                                            const float* __restrict__ sb1,
                                            const float* __restrict__ tb1,
                                            const float* __restrict__ nmeh,
                                            const float* __restrict__ ct,
                                            const float* __restrict__ sb2,
                                            float* __restrict__ hgf,
                                            float* __restrict__ out0) {
  int l = threadIdx.x, lr = l & 15, lg = l >> 4;
  int row0 = blockIdx.x * 16;
  int fo = focus[row0 + lr];
  f32x4 acc[8];
#pragma unroll
  for (int j = 0; j < 8; ++j) acc[j] = (f32x4){0.f, 0.f, 0.f, 0.f};
#pragma unroll
  for (int c2 = 0; c2 < 12; ++c2) {
    const float* ap;
    if (c2 < 4)      ap = imr + (size_t)(row0 + lr) * 128 + c2 * 32;
    else if (c2 < 8) ap = pgr + (size_t)(row0 + lr) * 128 + (c2 - 4) * 32;
    else             ap = nr + (size_t)fo * 128 + (c2 - 8) * 32;
    ap += lg * 8;
    bf16x8 aF = __builtin_bit_cast(bf16x8, pack8(*(const f32x4*)ap, *(const f32x4*)(ap + 4)));
    bf16x8 bF[8];
#pragma unroll
    for (int fn = 0; fn < 8; ++fn)
      bF[fn] = *(const bf16x8*)((const char*)wfrag + (size_t)(c2 * 8 + fn) * 1024 + l * 16);
#pragma unroll
    for (int fn = 0; fn < 8; ++fn)
      acc[fn] = __builtin_amdgcn_mfma_f32_16x16x32_bf16(aF, bF[fn], acc[fn], 0, 0, 0);
  }
  f32x4 sb1v, tb1v;
#pragma unroll
  for (int fn = 0; fn < 4; ++fn) {
    sb1v[fn] = sb1[fn * 16 + lr];
    tb1v[fn] = tb1[fn * 16 + lr];
  }
  f32x4 nmv = *(const f32x4*)(nmeh + lr * 8);
  f32x4 w2v = *(const f32x4*)(ct + 3 * 128 + lr * 8);
  float sb2v = sb2[0];
#pragma unroll
  for (int rg = 0; rg < 4; ++rg) {
    int g = row0 + lg * 4 + rg;
    f32x4 v0, v1;
#pragma unroll
    for (int fn = 0; fn < 4; ++fn) v0[fn] = acc[fn][rg] + sb1v[fn];
#pragma unroll
    for (int fn = 0; fn < 4; ++fn) v1[fn] = acc[fn + 4][rg] + tb1v[fn];
    *(f32x4*)(hgf + (size_t)g * 128 + lr * 8) = v0;
    *(f32x4*)(hgf + (size_t)g * 128 + lr * 8 + 4) = v1;
    float sp = 0.f;
#pragma unroll
    for (int i = 0; i < 4; ++i) sp += fmaxf(v0[i] + nmv[i], 0.f) * w2v[i];
#pragma unroll
    for (int m = 1; m < 16; m <<= 1) sp += __shfl_xor(sp, m, 64);
    if (lr == 0) out0[E_CNT + g] = sp + sb2v;
  }
}

// ---------- k_final: node-tile MFMA (h in f32 regs) + CSR edge sweep -------
// 2 waves/block, each wave owns 16 nodes (rows). After MFMA + HGF add, lane
// lr of slice lg holds units {fn*16+lr} of nodes base..base+3 in acc[fn][rg].
// Slice walks its contiguous sorted-edge range [offs[base], offs[base+4]) with
// 1-ahead eid->feats prefetch; rg comes packed in eid bits 20-21; h selected
// by 3-cndmask trees; dual head + dpp_red16; scattered dword stores.
__global__ __launch_bounds__(128) void k_final(
    const float* __restrict__ nr, const u16* __restrict__ wfrag,
    const int* __restrict__ n2g, const float* __restrict__ hgf,
    const int* __restrict__ offs, const int* __restrict__ eid,
    const float4* __restrict__ feats, const float* __restrict__ dtab,
    const float* __restrict__ ct, const float* __restrict__ sb2,
    const float* __restrict__ tb2, float* __restrict__ out0,
    float* __restrict__ out1) {
  int tid = threadIdx.x;
  int w = tid >> 6, l = tid & 63, lr = l & 15, lg = l >> 4;
  int row0 = blockIdx.x * 32 + w * 16;

  // ---- h = NR x W1c[384:512] for rows row0..row0+15 ----
  f32x4 acc[8];
#pragma unroll
  for (int j = 0; j < 8; ++j) acc[j] = (f32x4){0.f, 0.f, 0.f, 0.f};
#pragma unroll
  for (int c2 = 0; c2 < 4; ++c2) {
    const float* ap = nr + (size_t)(row0 + lr) * 128 + c2 * 32 + lg * 8;
    bf16x8 aF = __builtin_bit_cast(bf16x8, pack8(*(const f32x4*)ap, *(const f32x4*)(ap + 4)));
    bf16x8 bF[8];
#pragma unroll
    for (int fn = 0; fn < 8; ++fn)
      bF[fn] = *(const bf16x8*)((const char*)wfrag + (size_t)((12 + c2) * 8 + fn) * 1024 + l * 16);
#pragma unroll
    for (int fn = 0; fn < 8; ++fn)
      acc[fn] = __builtin_amdgcn_mfma_f32_16x16x32_bf16(aF, bF[fn], acc[fn], 0, 0, 0);
  }
  // ---- + HGF[n2g[m]] (h stays f32 in registers) ----
#pragma unroll
  for (int rg = 0; rg < 4; ++rg) {
    int m = row0 + lg * 4 + rg;
    int g = n2g[m];
    f32x4 v0 = *(const f32x4*)(hgf + (size_t)g * 128 + lr * 8);
    f32x4 v1 = *(const f32x4*)(hgf + (size_t)g * 128 + lr * 8 + 4);
#pragma unroll
    for (int i = 0; i < 4; ++i) { acc[i][rg] += v0[i]; acc[i + 4][rg] += v1[i]; }
  }

  // ---- per-lane head weights (q = lr) ----
  int q = lr;
  f32x4 wf1a = *(const f32x4*)(ct + 0 * 128 + q * 8), wf1b = *(const f32x4*)(ct + 0 * 128 + q * 8 + 4);
  f32x4 wf2a = *(const f32x4*)(ct + 1 * 128 + q * 8), wf2b = *(const f32x4*)(ct + 1 * 128 + q * 8 + 4);
  f32x4 wf3a = *(const f32x4*)(ct + 2 * 128 + q * 8), wf3b = *(const f32x4*)(ct + 2 * 128 + q * 8 + 4);
  f32x4 w2v  = *(const f32x4*)(ct + 3 * 128 + q * 8);
  f32x4 tw0v = *(const f32x4*)(ct + 4 * 128 + q * 8 + 4);
  f32x4 tw1v = *(const f32x4*)(ct + 5 * 128 + q * 8 + 4);
  f32x4 tw2v = *(const f32x4*)(ct + 6 * 128 + q * 8 + 4);
  f32x4 w5a  = *(const f32x4*)(ct + 7 * 128 + q * 8), w5b = *(const f32x4*)(ct + 7 * 128 + q * 8 + 4);
  float sb2v = sb2[0], tb0 = tb2[0], tb1 = tb2[1], tb2s = tb2[2];

  // ---- CSR edge sweep: slice lg owns nodes base..base+3 ----
  int base = row0 + lg * 4;
  int i = offs[base];
  int end = offs[base + 4];
  int vc = 0; float4 fc = make_float4(0.f, 0.f, 0.f, 0.f);
  if (i < end) { vc = eid[i]; fc = feats[vc & 0xFFFFF]; }
  while (__any(i < end)) {
    int in_ = i + 1;
    int vn = 0; float4 fn_ = fc;
    if (in_ < end) { vn = eid[in_]; fn_ = feats[vn & 0xFFFFF]; }  // prefetch
    if (i < end) {
      int e = vc & 0xFFFFF;
      int rg = (vc >> 20) & 3;
      float fd = dtab[(int)fminf(fc.x, 9.f)];
      float s = 0.f, a0 = 0.f, a1 = 0.f, a2 = 0.f;
#pragma unroll
      for (int ii = 0; ii < 4; ++ii) {
        float h = sel4(acc[ii], rg) + fd * w5a[ii] + fc.y * wf1a[ii] + fc.z * wf2a[ii] + fc.w * wf3a[ii];
        s += fmaxf(h, 0.f) * w2v[ii];
      }
#pragma unroll
      for (int ii = 0; ii < 4; ++ii) {
        float h = sel4(acc[ii + 4], rg) + fd * w5b[ii] + fc.y * wf1b[ii] + fc.z * wf2b[ii] + fc.w * wf3b[ii];
        float r = fmaxf(h, 0.f);
        a0 += r * tw0v[ii]; a1 += r * tw1v[ii]; a2 += r * tw2v[ii];
      }
      s = dpp_red16(s); a0 = dpp_red16(a0); a1 = dpp_red16(a1); a2 = dpp_red16(a2);
      if (lr == 0) {
        out0[e] = s + sb2v;
        float* o = out1 + (size_t)e * 3;
        o[0] = a0 + tb0; o[1] = a1 + tb1; o[2] = a2 + tb2s;
      }
    }
    i = in_; vc = vn; fc = fn_;
  }
}

extern "C" void kernel_launch(void* const* d_in, const int* in_sizes, int n_in,
                              void* d_out, int out_size, void* d_ws, size_t ws_size,
                              hipStream_t stream) {
  const float* imr   = (const float*)d_in[0];
  const float* pgr   = (const float*)d_in[1];
  const float* nr    = (const float*)d_in[2];
  const int*   focus = (const int*)d_in[3];
  const int*   n2g   = (const int*)d_in[4];
  const int*   tgt   = (const int*)d_in[5];
  const float* feats = (const float*)d_in[6];
  const float* dtab  = (const float*)d_in[8];
  const float* nme   = (const float*)d_in[9];
  const float* sW1   = (const float*)d_in[10];
  const float* sb1   = (const float*)d_in[11];
  const float* sW2   = (const float*)d_in[12];
  const float* sb2   = (const float*)d_in[13];
  const float* tW1   = (const float*)d_in[14];
  const float* tb1   = (const float*)d_in[15];
  const float* tW2   = (const float*)d_in[16];
  const float* tb2   = (const float*)d_in[17];

  char* ws = (char*)d_ws;
  float* HGF   = (float*)(ws + WS_HGF);
  u16*   WFRAG = (u16*)(ws + WS_WFRAG);
  float* CT    = (float*)(ws + WS_CT);
  float* NMEH  = (float*)(ws + WS_NMEH);
  int*   BINS  = (int*)(ws + WS_BINS);
  int*   OFFS  = (int*)(ws + WS_OFFS);
  int*   CURS  = (int*)(ws + WS_CURS);
  int*   EID   = (int*)(ws + WS_EID);

  float* out0 = (float*)d_out;            // [401024]
  float* out1 = out0 + (E_CNT + G_CNT);   // [400000*3]

  k_prep<<<321, 256, 0, stream>>>(nme, sW1, tW1, sW2, tW2, WFRAG, CT, NMEH, BINS);
  k_hist<<<1563, 256, 0, stream>>>(tgt, BINS);
  k_scan<<<1, 1024, 0, stream>>>(BINS, OFFS, CURS);
  k_scatter<<<1563, 256, 0, stream>>>(tgt, CURS, EID);
  k_hgf<<<64, 64, 0, stream>>>(imr, pgr, nr, focus, WFRAG, sb1, tb1, NMEH, CT, sb2, HGF, out0);
  k_final<<<2048, 128, 0, stream>>>(nr, WFRAG, n2g, HGF, OFFS, EID,
                                    (const float4*)feats, dtab, CT, sb2, tb2, out0, out1);
}

// Round 12
// 61.810 us; speedup vs baseline: 2.7009x; 2.7009x over previous
//
#include <hip/hip_runtime.h>

using u16    = unsigned short;
using f32x4  = __attribute__((ext_vector_type(4))) float;
using bf16x8 = __attribute__((ext_vector_type(8))) __bf16;

#define E_CNT 400000
#define G_CNT 1024

// ws layout (bytes)
#define WS_HND   0u          // H_node [65536][128] bf16 (permuted) = 16777216
#define WS_HGF   16777216u   // [1024][128] f32  (permuted, +b1)    =   524288
#define WS_WFRAG 17301504u   // [16][8][64] x 16B bf16 W1c frags    =   131072
#define WS_CT    17432576u   // [8][128] f32 (permuted)             =     4096
#define WS_NMEH  17436672u   // [128] f32 (permuted)                =      512

__device__ __forceinline__ u16 f2bf(float f) {
  unsigned u = __builtin_bit_cast(unsigned, f);
  return (u16)((u + 0x7fffu + ((u >> 16) & 1u)) >> 16);  // RNE
}
__device__ __forceinline__ float b2f(u16 v) {
  unsigned u = ((unsigned)v) << 16;
  return __builtin_bit_cast(float, u);
}
__device__ __forceinline__ uint4 pack8(f32x4 a, f32x4 b) {
  uint4 r;
  r.x = (unsigned)f2bf(a[0]) | ((unsigned)f2bf(a[1]) << 16);
  r.y = (unsigned)f2bf(a[2]) | ((unsigned)f2bf(a[3]) << 16);
  r.z = (unsigned)f2bf(b[0]) | ((unsigned)f2bf(b[1]) << 16);
  r.w = (unsigned)f2bf(b[2]) | ((unsigned)f2bf(b[3]) << 16);
  return r;
}
__device__ __forceinline__ float w1c(const float* sW1, const float* tW1, int k, int j) {
  return (j < 64) ? sW1[(size_t)k * 64 + j] : tW1[(size_t)k * 64 + (j - 64)];
}
// 16-lane sum via DPP (VALU pipe only; no LDS pipe, no waits)
__device__ __forceinline__ float dpp_red16(float x) {
  int v;
  v = __builtin_amdgcn_update_dpp(0, __builtin_bit_cast(int, x), 0xB1, 0xF, 0xF, false);
  x += __builtin_bit_cast(float, v);
  v = __builtin_amdgcn_update_dpp(0, __builtin_bit_cast(int, x), 0x4E, 0xF, 0xF, false);
  x += __builtin_bit_cast(float, v);
  v = __builtin_amdgcn_update_dpp(0, __builtin_bit_cast(int, x), 0x141, 0xF, 0xF, false);
  x += __builtin_bit_cast(float, v);
  v = __builtin_amdgcn_update_dpp(0, __builtin_bit_cast(int, x), 0x140, 0xF, 0xF, false);
  x += __builtin_bit_cast(float, v);
  return x;
}

// ---------- precompute: WFRAG + permuted small tables ----------
__global__ __launch_bounds__(256) void k_prep(const float* __restrict__ nme,
                                              const float* __restrict__ sW1,
                                              const float* __restrict__ tW1,
                                              const float* __restrict__ sW2,
                                              const float* __restrict__ tW2,
                                              u16* __restrict__ wfrag,
                                              float* __restrict__ ct,
                                              float* __restrict__ nmeh) {
  int b = blockIdx.x;
  if (b < 256) {
    int idx = b * 256 + threadIdx.x;  // 65536 total
    int j = idx & 7, l = (idx >> 3) & 63, fn = (idx >> 9) & 7, c = idx >> 12;
    int col = fn * 16 + (l & 15);
    int k = c * 32 + (l >> 4) * 8 + j;
    wfrag[idx] = f2bf(w1c(sW1, tW1, k, col));
  } else {
    int p = threadIdx.x;
    if (p >= 128) return;
    int q = p >> 3, i = p & 7, j = i * 16 + q;
    ct[0 * 128 + p] = w1c(sW1, tW1, 513, j);
    ct[1 * 128 + p] = w1c(sW1, tW1, 514, j);
    ct[2 * 128 + p] = w1c(sW1, tW1, 515, j);
    ct[3 * 128 + p] = (i < 4) ? sW2[j] : 0.f;
    if (i >= 4) {
      int jj = j - 64;
      ct[4 * 128 + p] = tW2[jj * 3 + 0];
      ct[5 * 128 + p] = tW2[jj * 3 + 1];
      ct[6 * 128 + p] = tW2[jj * 3 + 2];
    } else {
      ct[4 * 128 + p] = 0.f; ct[5 * 128 + p] = 0.f; ct[6 * 128 + p] = 0.f;
    }
    ct[7 * 128 + p] = w1c(sW1, tW1, 512, j);
    float s = 0.f;
    for (int k = 0; k < 132; ++k) s += nme[k] * w1c(sW1, tW1, 384 + k, j);
    nmeh[p] = s;
  }
}

// ---------- H_gf[1024][128] f32 (+b1) permuted, with STOP head fused -------
__global__ __launch_bounds__(64) void k_hgf(const float* __restrict__ imr,
                                            const float* __restrict__ pgr,
                                            const float* __restrict__ nr,
                                            const int* __restrict__ focus,
                                            const u16* __restrict__ wfrag,
                                            const float* __restrict__ sb1,
                                            const float* __restrict__ tb1,
                                            const float* __restrict__ nmeh,
                                            const float* __restrict__ ct,
                                            const float* __restrict__ sb2,
                                            float* __restrict__ hgf,
                                            float* __restrict__ out0) {
  int l = threadIdx.x, lr = l & 15, lg = l >> 4;
  int row0 = blockIdx.x * 16;
  int fo = focus[row0 + lr];
  f32x4 acc[8];
#pragma unroll
  for (int j = 0; j < 8; ++j) acc[j] = (f32x4){0.f, 0.f, 0.f, 0.f};
#pragma unroll
  for (int c2 = 0; c2 < 12; ++c2) {
    const float* ap;
    if (c2 < 4)      ap = imr + (size_t)(row0 + lr) * 128 + c2 * 32;
    else if (c2 < 8) ap = pgr + (size_t)(row0 + lr) * 128 + (c2 - 4) * 32;
    else             ap = nr + (size_t)fo * 128 + (c2 - 8) * 32;
    ap += lg * 8;
    bf16x8 aF = __builtin_bit_cast(bf16x8, pack8(*(const f32x4*)ap, *(const f32x4*)(ap + 4)));
    bf16x8 bF[8];
#pragma unroll
    for (int fn = 0; fn < 8; ++fn)
      bF[fn] = *(const bf16x8*)((const char*)wfrag + (size_t)(c2 * 8 + fn) * 1024 + l * 16);
#pragma unroll
    for (int fn = 0; fn < 8; ++fn)
      acc[fn] = __builtin_amdgcn_mfma_f32_16x16x32_bf16(aF, bF[fn], acc[fn], 0, 0, 0);
  }
  f32x4 sb1v, tb1v;
#pragma unroll
  for (int fn = 0; fn < 4; ++fn) {
    sb1v[fn] = sb1[fn * 16 + lr];
    tb1v[fn] = tb1[fn * 16 + lr];
  }
  f32x4 nmv = *(const f32x4*)(nmeh + lr * 8);
  f32x4 w2v = *(const f32x4*)(ct + 3 * 128 + lr * 8);
  float sb2v = sb2[0];
#pragma unroll
  for (int rg = 0; rg < 4; ++rg) {
    int g = row0 + lg * 4 + rg;
    f32x4 v0, v1;
#pragma unroll
    for (int fn = 0; fn < 4; ++fn) v0[fn] = acc[fn][rg] + sb1v[fn];
#pragma unroll
    for (int fn = 0; fn < 4; ++fn) v1[fn] = acc[fn + 4][rg] + tb1v[fn];
    *(f32x4*)(hgf + (size_t)g * 128 + lr * 8) = v0;
    *(f32x4*)(hgf + (size_t)g * 128 + lr * 8 + 4) = v1;
    float sp = 0.f;
#pragma unroll
    for (int i = 0; i < 4; ++i) sp += fmaxf(v0[i] + nmv[i], 0.f) * w2v[i];
#pragma unroll
    for (int m = 1; m < 16; m <<= 1) sp += __shfl_xor(sp, m, 64);
    if (lr == 0) out0[E_CNT + g] = sp + sb2v;
  }
}

// ---------- H_node[t] = NR[t] x W1c[384:512]  +  HGF[n2g[t]]  (bf16) -------
__global__ __launch_bounds__(64) void k_hnode(const float* __restrict__ nr,
                                              const u16* __restrict__ wfrag,
                                              const int* __restrict__ n2g,
                                              const float* __restrict__ hgf,
                                              u16* __restrict__ hnode) {
  int l = threadIdx.x, lr = l & 15, lg = l >> 4;
  int row0 = blockIdx.x * 16;
  f32x4 acc[8];
#pragma unroll
  for (int j = 0; j < 8; ++j) acc[j] = (f32x4){0.f, 0.f, 0.f, 0.f};
#pragma unroll
  for (int c2 = 0; c2 < 4; ++c2) {
    const float* ap = nr + (size_t)(row0 + lr) * 128 + c2 * 32 + lg * 8;
    bf16x8 aF = __builtin_bit_cast(bf16x8, pack8(*(const f32x4*)ap, *(const f32x4*)(ap + 4)));
    bf16x8 bF[8];
#pragma unroll
    for (int fn = 0; fn < 8; ++fn)
      bF[fn] = *(const bf16x8*)((const char*)wfrag + (size_t)((12 + c2) * 8 + fn) * 1024 + l * 16);
#pragma unroll
    for (int fn = 0; fn < 8; ++fn)
      acc[fn] = __builtin_amdgcn_mfma_f32_16x16x32_bf16(aF, bF[fn], acc[fn], 0, 0, 0);
  }
#pragma unroll
  for (int rg = 0; rg < 4; ++rg) {
    int m = row0 + lg * 4 + rg;
    int g = n2g[m];
    f32x4 v0 = *(const f32x4*)(hgf + (size_t)g * 128 + lr * 8);
    f32x4 v1 = *(const f32x4*)(hgf + (size_t)g * 128 + lr * 8 + 4);
    f32x4 s0, s1;
#pragma unroll
    for (int i = 0; i < 4; ++i) { s0[i] = acc[i][rg] + v0[i]; s1[i] = acc[i + 4][rg] + v1[i]; }
    *(uint4*)(hnode + (size_t)m * 128 + lr * 8) = pack8(s0, s1);
  }
}

// ---------- hot kernel: ONE gather per edge + elementwise + dual head ------
// 16 lanes/edge, lane q owns permuted units p=q*8..+7. 4 consecutive edges
// per slice (all loads issued up front = 4 independent chains), DPP
// reductions (no LDS pipe), float4-coalesced stores.
__global__ __launch_bounds__(256) void k_edge(
    const u16* __restrict__ hnode, const float* __restrict__ ct,
    const int* __restrict__ tgt, const float4* __restrict__ feats,
    const float* __restrict__ dtab, const float* __restrict__ sb2,
    const float* __restrict__ tb2, float* __restrict__ out0,
    float* __restrict__ out1) {
  int tid = threadIdx.x;
  int q = tid & 15;
  int e0 = blockIdx.x * 64 + (tid >> 4) * 4;

  f32x4 wf1a = *(const f32x4*)(ct + 0 * 128 + q * 8), wf1b = *(const f32x4*)(ct + 0 * 128 + q * 8 + 4);
  f32x4 wf2a = *(const f32x4*)(ct + 1 * 128 + q * 8), wf2b = *(const f32x4*)(ct + 1 * 128 + q * 8 + 4);
  f32x4 wf3a = *(const f32x4*)(ct + 2 * 128 + q * 8), wf3b = *(const f32x4*)(ct + 2 * 128 + q * 8 + 4);
  f32x4 w2v  = *(const f32x4*)(ct + 3 * 128 + q * 8);
  f32x4 tw0v = *(const f32x4*)(ct + 4 * 128 + q * 8 + 4);
  f32x4 tw1v = *(const f32x4*)(ct + 5 * 128 + q * 8 + 4);
  f32x4 tw2v = *(const f32x4*)(ct + 6 * 128 + q * 8 + 4);
  f32x4 w5a  = *(const f32x4*)(ct + 7 * 128 + q * 8), w5b = *(const f32x4*)(ct + 7 * 128 + q * 8 + 4);
  float sb2v = sb2[0], tb0 = tb2[0], tb1 = tb2[1], tb2s = tb2[2];

  int t[4];
#pragma unroll
  for (int j = 0; j < 4; ++j) t[j] = tgt[e0 + j];
  float4 f[4];
#pragma unroll
  for (int j = 0; j < 4; ++j) f[j] = feats[e0 + j];
  union { uint4 v; u16 s[8]; } hn[4];
#pragma unroll
  for (int j = 0; j < 4; ++j)
    hn[j].v = *(const uint4*)(hnode + (size_t)t[j] * 128 + q * 8);
  float fd[4];
#pragma unroll
  for (int j = 0; j < 4; ++j) fd[j] = dtab[(int)fminf(f[j].x, 9.f)];

  float sc[4], t0[4], t1[4], t2[4];
#pragma unroll
  for (int j = 0; j < 4; ++j) {
    float s = 0.f, a0 = 0.f, a1 = 0.f, a2 = 0.f;
#pragma unroll
    for (int i = 0; i < 4; ++i) {
      float h = b2f(hn[j].s[i]) + fd[j] * w5a[i] + f[j].y * wf1a[i] + f[j].z * wf2a[i] + f[j].w * wf3a[i];
      s += fmaxf(h, 0.f) * w2v[i];
    }
#pragma unroll
    for (int i = 0; i < 4; ++i) {
      float h = b2f(hn[j].s[4 + i]) + fd[j] * w5b[i] + f[j].y * wf1b[i] + f[j].z * wf2b[i] + f[j].w * wf3b[i];
      float r = fmaxf(h, 0.f);
      a0 += r * tw0v[i]; a1 += r * tw1v[i]; a2 += r * tw2v[i];
    }
    sc[j] = s; t0[j] = a0; t1[j] = a1; t2[j] = a2;
  }
#pragma unroll
  for (int j = 0; j < 4; ++j) {
    sc[j] = dpp_red16(sc[j]); t0[j] = dpp_red16(t0[j]);
    t1[j] = dpp_red16(t1[j]); t2[j] = dpp_red16(t2[j]);
  }
  if (q == 0) {
    *(float4*)(out0 + e0) = make_float4(sc[0] + sb2v, sc[1] + sb2v, sc[2] + sb2v, sc[3] + sb2v);
    float* o = out1 + (size_t)e0 * 3;  // 12 consecutive f32, 16B-aligned
    *(float4*)(o + 0) = make_float4(t0[0] + tb0, t1[0] + tb1, t2[0] + tb2s, t0[1] + tb0);
    *(float4*)(o + 4) = make_float4(t1[1] + tb1, t2[1] + tb2s, t0[2] + tb0, t1[2] + tb1);
    *(float4*)(o + 8) = make_float4(t2[2] + tb2s, t0[3] + tb0, t1[3] + tb1, t2[3] + tb2s);
  }
}

extern "C" void kernel_launch(void* const* d_in, const int* in_sizes, int n_in,
                              void* d_out, int out_size, void* d_ws, size_t ws_size,
                              hipStream_t stream) {
  const float* imr   = (const float*)d_in[0];
  const float* pgr   = (const float*)d_in[1];
  const float* nr    = (const float*)d_in[2];
  const int*   focus = (const int*)d_in[3];
  const int*   n2g   = (const int*)d_in[4];
  const int*   tgt   = (const int*)d_in[5];
  const float* feats = (const float*)d_in[6];
  const float* dtab  = (const float*)d_in[8];
  const float* nme   = (const float*)d_in[9];
  const float* sW1   = (const float*)d_in[10];
  const float* sb1   = (const float*)d_in[11];
  const float* sW2   = (const float*)d_in[12];
  const float* sb2   = (const float*)d_in[13];
  const float* tW1   = (const float*)d_in[14];
  const float* tb1   = (const float*)d_in[15];
  const float* tW2   = (const float*)d_in[16];
  const float* tb2   = (const float*)d_in[17];

  char* ws = (char*)d_ws;
  u16*   HND   = (u16*)(ws + WS_HND);
  float* HGF   = (float*)(ws + WS_HGF);
  u16*   WFRAG = (u16*)(ws + WS_WFRAG);
  float* CT    = (float*)(ws + WS_CT);
  float* NMEH  = (float*)(ws + WS_NMEH);

  float* out0 = (float*)d_out;            // [401024]
  float* out1 = out0 + (E_CNT + G_CNT);   // [400000*3]

  k_prep<<<257, 256, 0, stream>>>(nme, sW1, tW1, sW2, tW2, WFRAG, CT, NMEH);
  k_hgf<<<64, 64, 0, stream>>>(imr, pgr, nr, focus, WFRAG, sb1, tb1, NMEH, CT, sb2, HGF, out0);
  k_hnode<<<4096, 64, 0, stream>>>(nr, WFRAG, n2g, HGF, HND);
  k_edge<<<6250, 256, 0, stream>>>(HND, CT, tgt, (const float4*)feats,
                                   dtab, sb2, tb2, out0, out1);
}